// Round 2
// baseline (2436.344 us; speedup 1.0000x reference)
//
#include <hip/hip_runtime.h>
#include <stdint.h>

#define B_  256
#define T_  512
#define I_  256
#define H_  512
#define G3_ 1536

typedef _Float16 half8  __attribute__((ext_vector_type(8)));
typedef _Float16 half4v __attribute__((ext_vector_type(4)));
typedef float    float4v __attribute__((ext_vector_type(4)));

__device__ __forceinline__ float sigmoid_f(float x) { return 1.f / (1.f + __expf(-x)); }
__device__ __forceinline__ float tanh_f(float x) {
  x = fminf(15.f, fmaxf(-15.f, x));
  float e = __expf(2.f * x);
  return (e - 1.f) / (e + 1.f);
}

union H16 { _Float16 h; unsigned short u; };

// ---------------------------------------------------------------------------
// Kernel A: igates[t][b][g] = (fp16) sum_k x[b][t][k] * w_ih[g][k] + bias[g]
// (unchanged — proven in round 0; scan dominates)
// ---------------------------------------------------------------------------
__global__ __launch_bounds__(256) void igates_gemm(
    const float* __restrict__ x, const float* __restrict__ w_ih,
    const float* __restrict__ bias, _Float16* __restrict__ ig)
{
  __shared__ _Float16 Ash[64][72];
  __shared__ _Float16 Bsh[64][72];
  const int tid  = threadIdx.x;
  const int lane = tid & 63;
  const int wv   = tid >> 6;
  const int wm   = wv >> 1, wn = wv & 1;
  const int n0   = blockIdx.x * 64;
  const int m0   = blockIdx.y * 64;

  float4v acc[2][2];
  #pragma unroll
  for (int a = 0; a < 2; ++a)
    #pragma unroll
    for (int c = 0; c < 2; ++c) acc[a][c] = (float4v){0.f, 0.f, 0.f, 0.f};

  for (int kc = 0; kc < I_; kc += 64) {
    #pragma unroll
    for (int i = 0; i < 4; ++i) {
      int e   = tid + (i << 8);
      int row = e >> 4;
      int c4  = e & 15;
      int m   = m0 + row;
      int tt  = m >> 8, bb = m & 255;
      float4 va = *(const float4*)(x + ((size_t)bb * T_ + tt) * I_ + kc + (c4 << 2));
      *(half4v*)&Ash[row][c4 << 2] =
          (half4v){(_Float16)va.x, (_Float16)va.y, (_Float16)va.z, (_Float16)va.w};
      float4 vb = *(const float4*)(w_ih + (size_t)(n0 + row) * I_ + kc + (c4 << 2));
      *(half4v*)&Bsh[row][c4 << 2] =
          (half4v){(_Float16)vb.x, (_Float16)vb.y, (_Float16)vb.z, (_Float16)vb.w};
    }
    __syncthreads();
    #pragma unroll
    for (int ks = 0; ks < 2; ++ks) {
      int kk = (ks << 5) + ((lane >> 4) << 3);
      half8 a0 = *(const half8*)&Ash[(wm << 5) + (lane & 15)][kk];
      half8 a1 = *(const half8*)&Ash[(wm << 5) + 16 + (lane & 15)][kk];
      half8 b0 = *(const half8*)&Bsh[(wn << 5) + (lane & 15)][kk];
      half8 b1 = *(const half8*)&Bsh[(wn << 5) + 16 + (lane & 15)][kk];
      acc[0][0] = __builtin_amdgcn_mfma_f32_16x16x32_f16(a0, b0, acc[0][0], 0, 0, 0);
      acc[0][1] = __builtin_amdgcn_mfma_f32_16x16x32_f16(a0, b1, acc[0][1], 0, 0, 0);
      acc[1][0] = __builtin_amdgcn_mfma_f32_16x16x32_f16(a1, b0, acc[1][0], 0, 0, 0);
      acc[1][1] = __builtin_amdgcn_mfma_f32_16x16x32_f16(a1, b1, acc[1][1], 0, 0, 0);
    }
    __syncthreads();
  }
  #pragma unroll
  for (int mt = 0; mt < 2; ++mt)
    #pragma unroll
    for (int nt = 0; nt < 2; ++nt) {
      int mrow = m0 + (wm << 5) + (mt << 4) + ((lane >> 4) << 2);
      int ncol = n0 + (wn << 5) + (nt << 4) + (lane & 15);
      float bb = bias[ncol];
      #pragma unroll
      for (int r = 0; r < 4; ++r)
        ig[(size_t)(mrow + r) * G3_ + ncol] = (_Float16)(acc[mt][nt][r] + bb);
    }
}

// ---------------------------------------------------------------------------
// Kernel B: persistent GRU scan, v4 — v2's proven geometry (128 WGs x 256 thr,
// 4 waves, 1 wave/SIMD, 512-VGPR budget: no spill) + v3's flag-free
// self-validating exchange.
//
// Each published h element is one u32:  (fp16_bits << 16) | ((t+1) & 0xffff)
// stored with a single relaxed agent-scope atomic (write-through at the
// coherence point). Value and step tag are inseparable, so consumers validate
// freshness from the data itself: no producer s_waitcnt(0) ack, no flag
// store, no flag spin, and only ONE __syncthreads per step (LDS h is
// double-buffered by parity so staging for t+1 never touches buffers read at
// t; max cross-wave skew is one step).
//
// Safety: h double-buffered in global by step parity. A WG publishes tag t+2
// into parity t&1 only after its step-(t+1) poll saw tag t+1 from every WG of
// its b-group, and each of those WGs published t+1 only after its WG barrier,
// which orders it after ALL its waves finished reading tag t. So no word a
// consumer still needs can be overwritten. Buffers zeroed per launch: tag 0
// == h(0) == 0, so step 0 uses the same poll path.
//
// Bounded poll (hang-safety valve): if the protocol were ever violated the
// poll falls through after ~4M rounds with stale data -> wrong answer instead
// of a hung container. Never triggers when the protocol holds.
// ---------------------------------------------------------------------------
__global__ __launch_bounds__(256, 1) void gru_scan(
    const _Float16* __restrict__ ig, const float* __restrict__ w_hh,
    const float* __restrict__ b_n, uint32_t* __restrict__ hw)
{
  __shared__ _Float16 h_lds[2][16][520];   // double-buffered h(t): 16 b x 512 cols (+8 pad)

  const int tid   = threadIdx.x;
  const int lane  = tid & 63;
  const int wv    = tid >> 6;                 // wave 0..3
  const int blk   = blockIdx.x;
  // XCD co-location: all 8 slices of a b-group share blk&7. Perf-only.
  const int gb    = ((blk & 7) << 1) | ((blk >> 3) & 1);  // 0..15
  const int gs    = blk >> 4;                              // 0..7
  const int b0    = gb << 4;
  const int jw    = (gs << 6) + (wv << 4);    // first global h-col of this wave
  const int cn    = lane & 15;
  const int rquad = lane >> 4;

  // --- preload w_hh fragments (resident in VGPRs all 512 steps) ---
  half8 wfrag[3][16];
  #pragma unroll
  for (int g = 0; g < 3; ++g) {
    const float* wrow = w_hh + (size_t)(g * H_ + jw + cn) * H_;
    #pragma unroll
    for (int ks = 0; ks < 16; ++ks) {
      int k = (ks << 5) + (rquad << 3);
      half8 w;
      #pragma unroll
      for (int i = 0; i < 8; ++i) w[i] = (_Float16)wrow[k + i];
      wfrag[g][ks] = w;
    }
  }
  const float bnv = b_n[jw + cn];

  for (int t = 0; t < T_; ++t) {
    const int p = t & 1;

    // (A) ig prefetch — independent of peers, overlaps the poll latency
    float igv[3][4];
    {
      const _Float16* igb =
          ig + (size_t)(t * B_ + b0 + (rquad << 2)) * G3_ + jw + cn;
      #pragma unroll
      for (int g = 0; g < 3; ++g)
        #pragma unroll
        for (int r = 0; r < 4; ++r)
          igv[g][r] = (float)igb[(size_t)r * G3_ + g * H_];
    }

    // (B) poll+load full h(t) for this b-group: 16 rows x 512 tagged u32
    //     = 4096 u64 -> 16 u64/thread. Accept words whose BOTH tags == t.
    //     Batched reload of only-stale words; each round ~ one RT.
    const unsigned tag = (unsigned)t;
    const unsigned long long* hb =
        (const unsigned long long*)(hw + ((size_t)p * (B_ * H_)));
    unsigned long long w64[16];
    unsigned pend = 0xffffu;
    for (int spin = 0; __any(pend != 0u) && spin < (1 << 22); ++spin) {
      #pragma unroll
      for (int i = 0; i < 16; ++i)
        if (pend & (1u << i))
          w64[i] = __hip_atomic_load(hb + (((size_t)(b0 + i)) << 8) + tid,
                                     __ATOMIC_RELAXED, __HIP_MEMORY_SCOPE_AGENT);
      unsigned np = 0u;
      #pragma unroll
      for (int i = 0; i < 16; ++i)
        if (pend & (1u << i)) {
          unsigned lo = (unsigned)w64[i] & 0xffffu;
          unsigned hi = (unsigned)(w64[i] >> 32) & 0xffffu;
          if ((lo != tag) || (hi != tag)) np |= (1u << i);
        }
      pend = np;
    }

    // (C) stage into LDS buffer p (strip tags, pack 2 fp16 per u32 write)
    //     thread tid owns row i, u64-col tid -> LDS cols 2*tid, 2*tid+1
    #pragma unroll
    for (int i = 0; i < 16; ++i) {
      unsigned packed = ((unsigned)(w64[i] >> 16) & 0xffffu) |
                        ((unsigned)(w64[i] >> 48) << 16);
      *(unsigned*)&h_lds[p][i][tid << 1] = packed;
    }

    // (D) the ONLY barrier per step
    __syncthreads();

    // (E) MFMA: 3 gates x full K=512 per wave
    float4v acc[3];
    acc[0] = (float4v){0.f, 0.f, 0.f, 0.f};
    acc[1] = acc[0];
    acc[2] = acc[0];
    #pragma unroll
    for (int ks = 0; ks < 16; ++ks) {
      half8 a = *(const half8*)&h_lds[p][cn][(ks << 5) + (rquad << 3)];
      acc[0] = __builtin_amdgcn_mfma_f32_16x16x32_f16(a, wfrag[0][ks], acc[0], 0, 0, 0);
      acc[1] = __builtin_amdgcn_mfma_f32_16x16x32_f16(a, wfrag[1][ks], acc[1], 0, 0, 0);
      acc[2] = __builtin_amdgcn_mfma_f32_16x16x32_f16(a, wfrag[2][ks], acc[2], 0, 0, 0);
    }

    // (F) in-register epilogue + fire-and-forget tagged publish of h(t+1)
    uint32_t* hwout = hw + ((size_t)((t + 1) & 1) * (B_ * H_));
    const unsigned tagw = (unsigned)(t + 1);
    #pragma unroll
    for (int r = 0; r < 4; ++r) {
      float rg = sigmoid_f(igv[0][r] + acc[0][r]);
      float zg = sigmoid_f(igv[1][r] + acc[1][r]);
      float nv = tanh_f(igv[2][r] + rg * (acc[2][r] + bnv));
      float hp = (float)h_lds[p][(rquad << 2) + r][jw + cn];
      H16 hv; hv.h = (_Float16)(nv + zg * (hp - nv));
      __hip_atomic_store(
          hwout + (((size_t)(b0 + (rquad << 2) + r)) << 9) + jw + cn,
          ((unsigned)hv.u << 16) | tagw,
          __ATOMIC_RELAXED, __HIP_MEMORY_SCOPE_AGENT);
    }
  }
}

// ---------------------------------------------------------------------------
// Kernel C: e[b] = h_T[b] . w_proj + b_proj   (h_T tagged-u32, parity 0)
// ---------------------------------------------------------------------------
__global__ __launch_bounds__(64) void proj_kernel(
    const uint32_t* __restrict__ h, const float* __restrict__ w_proj,
    const float* __restrict__ b_proj, float* __restrict__ out)
{
  int b = blockIdx.x;
  int lane = threadIdx.x;
  float s = 0.f;
  #pragma unroll
  for (int i = 0; i < 8; ++i) {
    int j = lane + (i << 6);
    H16 v; v.u = (unsigned short)(h[((size_t)b << 9) + j] >> 16);
    s += (float)v.h * w_proj[j];
  }
  #pragma unroll
  for (int off = 32; off > 0; off >>= 1) s += __shfl_down(s, off, 64);
  if (lane == 0) out[b] = s + b_proj[0];
}

// ---------------------------------------------------------------------------
extern "C" void kernel_launch(void* const* d_in, const int* in_sizes, int n_in,
                              void* d_out, int out_size, void* d_ws, size_t ws_size,
                              hipStream_t stream) {
  const float* x      = (const float*)d_in[0];
  const float* w_ih   = (const float*)d_in[1];
  const float* w_hh   = (const float*)d_in[2];
  const float* bias   = (const float*)d_in[3];
  const float* b_n    = (const float*)d_in[4];
  const float* w_proj = (const float*)d_in[5];
  const float* b_proj = (const float*)d_in[6];
  float* out = (float*)d_out;

  char* ws = (char*)d_ws;
  const size_t IG_BYTES = (size_t)T_ * B_ * G3_ * sizeof(_Float16); // 402,653,184
  const size_t HW_BYTES = (size_t)B_ * H_ * sizeof(uint32_t);       // 524,288 per parity
  _Float16* igbuf = (_Float16*)ws;
  uint32_t* hw    = (uint32_t*)(ws + IG_BYTES);

  // zero both tagged-h parity buffers (tag 0 == h(0) == 0) — capture-safe
  hipMemsetAsync(hw, 0, 2 * HW_BYTES, stream);

  dim3 gridA(G3_ / 64, (T_ * B_) / 64);   // (24, 2048)
  igates_gemm<<<gridA, 256, 0, stream>>>(x, w_ih, bias, igbuf);
  gru_scan<<<128, 256, 0, stream>>>(igbuf, w_hh, b_n, hw);
  proj_kernel<<<B_, 64, 0, stream>>>(hw, w_proj, b_proj, out);
}